// Round 2
// baseline (30317.511 us; speedup 1.0000x reference)
//
#include <hip/hip_runtime.h>
#include <cstdint>
#include <cstddef>

typedef float f32x4 __attribute__((ext_vector_type(4)));
typedef __bf16 bf16x8 __attribute__((ext_vector_type(8)));
typedef unsigned short u16;
typedef unsigned int u32;
typedef unsigned short u16x8 __attribute__((ext_vector_type(8)));

#define DI __device__ __forceinline__

constexpr int T_ = 512, B_ = 64, D_ = 1024, H_ = 1024, N3_ = 3072;
constexpr int G_ = 256;   // recurrence blocks (1/CU on 256-CU chip)
constexpr int NH_ = 4;    // h-columns owned per recurrence block

// round-to-nearest-even fp32 -> bf16 bits
DI u16 f2bf(float f) {
  u32 u = __builtin_bit_cast(u32, f);
  return (u16)((u + 0x7FFFu + ((u >> 16) & 1u)) >> 16);
}
DI float bf2f(u16 h) { u32 u = (u32)h << 16; return __builtin_bit_cast(float, u); }

// ---------- Wi [D][3H] fp32 -> WiT_hi/lo [3H][D] bf16 (transpose + split) ----------
__global__ void k_wi(const float* __restrict__ wi, u16* __restrict__ wth, u16* __restrict__ wtl) {
  __shared__ u16 sh[64][66], sl[64][66];
  int d0 = (blockIdx.x & 15) << 6, n0 = (blockIdx.x >> 4) << 6;
  int cr = threadIdx.x >> 6, cc = threadIdx.x & 63;
#pragma unroll
  for (int r = 0; r < 16; ++r) {
    int row = r * 4 + cr;
    float v = wi[(size_t)(d0 + row) * N3_ + n0 + cc];
    u16 h = f2bf(v);
    sh[row][cc] = h; sl[row][cc] = f2bf(v - bf2f(h));
  }
  __syncthreads();
#pragma unroll
  for (int r = 0; r < 16; ++r) {
    int nr = r * 4 + cr;
    size_t o = (size_t)(n0 + nr) * D_ + d0 + cc;
    wth[o] = sh[cc][nr];
    wtl[o] = sl[cc][nr];
  }
}

__global__ void k_zero(u32* p, int n) {
  for (int i = blockIdx.x * blockDim.x + threadIdx.x; i < n; i += gridDim.x * blockDim.x) p[i] = 0u;
}

__global__ void k_fill(float* p, int n, float v) {
  for (int i = blockIdx.x * blockDim.x + threadIdx.x; i < n; i += gridDim.x * blockDim.x) p[i] = v;
}

// ---------- xi = x @ Wi  (A converted fp32->bf16 hi/lo in-kernel; split-bf16 3-term MFMA) ----------
__global__ __launch_bounds__(256) void k_gemm(
    const float* __restrict__ x,
    const u16* __restrict__ Bh, const u16* __restrict__ Bl,
    float* __restrict__ C) {
  // LDS layout [kg:4][row:128][8] per array -> conflict-free ds_read_b128, linear for global_load_lds
  __shared__ __align__(16) u16 sAh[4096], sAl[4096], sBh[4096], sBl[4096];
  // XCD-chunked swizzle: each XCD gets 32 contiguous m-panels x all 24 n-tiles (A-panel L2 reuse)
  int wg = ((blockIdx.x & 7) * 768) + (blockIdx.x >> 3);
  int m0 = (wg / 24) * 128, n0 = (wg % 24) * 128;
  int tid = threadIdx.x, w = tid >> 6, l = tid & 63;
  int lr = l & 15, lk = l >> 4;
  int wr = (w >> 1) * 64, wc = (w & 1) * 64;
  f32x4 acc[4][4] = {};
  for (int kt = 0; kt < 32; ++kt) {
    __syncthreads();
    if (tid < 128) {
      // waves 0,1: A-side. row = tid; fold the [b][t] -> m'=t*64+b permute into addressing.
      int m = m0 + tid;
      const float* src = x + ((size_t)(m & 63) * T_ + (m >> 6)) * D_ + kt * 32;
#pragma unroll
      for (int kg = 0; kg < 4; ++kg) {
        float4 v0 = *(const float4*)(src + kg * 8);
        float4 v1 = *(const float4*)(src + kg * 8 + 4);
        float vv[8] = {v0.x, v0.y, v0.z, v0.w, v1.x, v1.y, v1.z, v1.w};
        u16x8 h8, l8;
#pragma unroll
        for (int e = 0; e < 8; ++e) {
          u32 u = __builtin_bit_cast(u32, vv[e]);
          u16 hi = (u16)(u >> 16);              // truncation split: residual exactly captured by lo
          h8[e] = hi;
          l8[e] = f2bf(vv[e] - bf2f(hi));
        }
        *(u16x8*)(sAh + (kg * 128 + tid) * 8) = h8;
        *(u16x8*)(sAl + (kg * 128 + tid) * 8) = l8;
      }
    } else {
      // waves 2,3: B-side via global_load_lds width=16 (verified m97 pattern)
      const u16* gb = (tid < 192) ? Bh : Bl;
      u16* sb = (tid < 192) ? sBh : sBl;
#pragma unroll
      for (int i = 0; i < 8; ++i) {
        int kg = i >> 1, row = ((i & 1) << 6) + l;
        const u16* gp = gb + (size_t)(n0 + row) * D_ + kt * 32 + kg * 8;
        __builtin_amdgcn_global_load_lds((const __attribute__((address_space(1))) u32*)gp,
                                         (__attribute__((address_space(3))) u32*)(sb + i * 512), 16, 0, 0);
      }
    }
    __syncthreads();
    bf16x8 a_h[4], a_l[4], b_h[4], b_l[4];
#pragma unroll
    for (int i = 0; i < 4; ++i) {
      int ar = wr + i * 16 + lr;
      a_h[i] = *(const bf16x8*)(sAh + (lk * 128 + ar) * 8);
      a_l[i] = *(const bf16x8*)(sAl + (lk * 128 + ar) * 8);
      int bc = wc + i * 16 + lr;
      b_h[i] = *(const bf16x8*)(sBh + (lk * 128 + bc) * 8);
      b_l[i] = *(const bf16x8*)(sBl + (lk * 128 + bc) * 8);
    }
#pragma unroll
    for (int i = 0; i < 4; ++i)
#pragma unroll
      for (int j = 0; j < 4; ++j) {
        acc[i][j] = __builtin_amdgcn_mfma_f32_16x16x32_bf16(a_l[i], b_h[j], acc[i][j], 0, 0, 0);
        acc[i][j] = __builtin_amdgcn_mfma_f32_16x16x32_bf16(a_h[i], b_l[j], acc[i][j], 0, 0, 0);
        acc[i][j] = __builtin_amdgcn_mfma_f32_16x16x32_bf16(a_h[i], b_h[j], acc[i][j], 0, 0, 0);
      }
  }
  // C/D layout (HW-verified): col = lane&15, row = (lane>>4)*4 + reg
#pragma unroll
  for (int i = 0; i < 4; ++i)
#pragma unroll
    for (int j = 0; j < 4; ++j)
#pragma unroll
      for (int e = 0; e < 4; ++e) {
        int row = m0 + wr + i * 16 + lk * 4 + e;
        int col = n0 + wc + j * 16 + lr;
        C[(size_t)row * N3_ + col] = acc[i][j][e];
      }
}

// ---------- persistent recurrence: G=256 blocks, NH=4 cols/block, STATIC 56KB LDS ----------
DI float sigmf(float v) { return 1.f / (1.f + __expf(-v)); }
DI float tanhf_(float v) {
  float a = fabsf(v);
  float e = __expf(2.f * a);           // inf-safe: e=inf -> r=1
  float r = 1.f - 2.f / (e + 1.f);
  return v < 0.f ? -r : r;
}

__global__ __launch_bounds__(256, 1) void k_rnn(
    const float* __restrict__ xi,      // [t*64+b][3072]
    const float* __restrict__ Wh,      // [1024][3072] fp32
    const float* __restrict__ bh,      // [3072]
    u16* __restrict__ hb,              // hi0, lo0, hi1, lo1 (64*1024 u16 each)
    int* __restrict__ flags,           // [G_]
    float* __restrict__ out) {         // [B][T][H]
  // Wh slice: [kk=kt*4+kg : 128][col:12][8] hi+lo, tight stride 12 (+64 elem tail pad for
  // lr=12..15 garbage reads -> garbage confined to acc cols 12..15, ignored by gates)
  __shared__ __align__(16) u16 sWh[12352], sWl[12352];
  __shared__ float hh[2 * 64 * 13];    // k-half partials, stride 13
  const int g = blockIdx.x, tid = threadIdx.x;

  for (int idx = tid; idx < 12288; idx += 256) {
    int e = idx & 7, rest = idx >> 3;
    int col = rest % 12, kk = rest / 12;
    int k = (kk >> 2) * 32 + (kk & 3) * 8 + e;
    int n = (col >> 2) * 1024 + g * NH_ + (col & 3);   // cols [r0-3|z0-3|n0-3]
    float v = Wh[(size_t)k * N3_ + n];
    u32 u = __builtin_bit_cast(u32, v);
    u16 hi = (u16)(u >> 16);
    sWh[idx] = hi;
    sWl[idx] = f2bf(v - bf2f(hi));
  }
  const int jb = tid & 3, b = tid >> 2;
  float bhr = bh[g * NH_ + jb], bhz = bh[1024 + g * NH_ + jb], bhn = bh[2048 + g * NH_ + jb];
  float hp = 0.f;
  const int w = tid >> 6, l = tid & 63;
  const int mh = w >> 1, kh = w & 1, lr = l & 15, lk = l >> 4;
  u16* hbuf[2][2] = {{hb, hb + 65536}, {hb + 131072, hb + 196608}};
  __syncthreads();

  for (int t = 0; t < T_; ++t) {
    // xi loads are h-independent: issue before the wait
    const float* pp = xi + (size_t)(t * 64 + b) * N3_ + g * NH_ + jb;
    float xr = pp[0], xz = pp[1024], xn = pp[2048];
    if (t > 0) {
      while (__hip_atomic_load(&flags[tid], __ATOMIC_RELAXED, __HIP_MEMORY_SCOPE_AGENT) < t)
        __builtin_amdgcn_s_sleep(1);
      __threadfence();                 // acquire: make remote-XCD h writes visible
    }
    __syncthreads();
    const u16* chi = hbuf[t & 1][0];
    const u16* clo = hbuf[t & 1][1];

    // wave (mh,kh): rows mh*32..+32, k-half kh; A-frags straight from global h
    f32x4 acc[2] = {};
#pragma unroll 4
    for (int k2 = 0; k2 < 16; ++k2) {
      int kt = kh * 16 + k2;
      int sbase = ((kt * 4 + lk) * 12 + lr) * 8;
      bf16x8 b0h = *(const bf16x8*)(sWh + sbase);
      bf16x8 b0l = *(const bf16x8*)(sWl + sbase);
      int kb = kt * 32 + lk * 8;
#pragma unroll
      for (int m2 = 0; m2 < 2; ++m2) {
        int row = mh * 32 + m2 * 16 + lr;
        bf16x8 ah = *(const bf16x8*)(chi + row * 1024 + kb);
        bf16x8 al = *(const bf16x8*)(clo + row * 1024 + kb);
        acc[m2] = __builtin_amdgcn_mfma_f32_16x16x32_bf16(al, b0h, acc[m2], 0, 0, 0);
        acc[m2] = __builtin_amdgcn_mfma_f32_16x16x32_bf16(ah, b0l, acc[m2], 0, 0, 0);
        acc[m2] = __builtin_amdgcn_mfma_f32_16x16x32_bf16(ah, b0h, acc[m2], 0, 0, 0);
      }
    }
#pragma unroll
    for (int m2 = 0; m2 < 2; ++m2)
      if (lr < 12)
#pragma unroll
        for (int e = 0; e < 4; ++e) {
          int row = mh * 32 + m2 * 16 + lk * 4 + e;
          hh[(kh * 64 + row) * 13 + lr] = acc[m2][e];
        }
    __syncthreads();

    // fused gates: one (b,j) pair per thread; own h kept in register hp
    u16* nhi = hbuf[(t + 1) & 1][0];
    u16* nlo = hbuf[(t + 1) & 1][1];
    {
      float hr = hh[b * 13 + jb]     + hh[(64 + b) * 13 + jb]     + bhr;
      float hz = hh[b * 13 + 4 + jb] + hh[(64 + b) * 13 + 4 + jb] + bhz;
      float hn = hh[b * 13 + 8 + jb] + hh[(64 + b) * 13 + 8 + jb] + bhn;
      float r = sigmf(xr + hr);
      float z = sigmf(xz + hz);
      float n = tanhf_(xn + r * hn);
      float hv = (1.f - z) * n + z * hp;
      hp = hv;
      out[((size_t)b * T_ + t) * H_ + g * NH_ + jb] = hv;
      u32 u = __builtin_bit_cast(u32, hv);
      u16 hi = (u16)(u >> 16);
      nhi[b * 1024 + g * NH_ + jb] = hi;
      nlo[b * 1024 + g * NH_ + jb] = f2bf(hv - bf2f(hi));
    }
    __threadfence();                   // release: drain h stores before publishing
    __syncthreads();
    if (tid == 0) __hip_atomic_store(&flags[g], t + 1, __ATOMIC_RELAXED, __HIP_MEMORY_SCOPE_AGENT);
  }
}

extern "C" void kernel_launch(void* const* d_in, const int* in_sizes, int n_in,
                              void* d_out, int out_size, void* d_ws, size_t ws_size,
                              hipStream_t stream) {
  const float* x  = (const float*)d_in[0];
  const float* Wi = (const float*)d_in[1];
  const float* Wh = (const float*)d_in[2];
  const float* bh = (const float*)d_in[3];
  float* out = (float*)d_out;

  char* p = (char*)d_ws;
  float* xi = (float*)p;  p += (size_t)32768 * 3072 * 4;   // 402,653,184
  u16* wth = (u16*)p;     p += (size_t)3072 * 1024 * 2;    // 6,291,456
  u16* wtl = (u16*)p;     p += (size_t)3072 * 1024 * 2;
  u16* hb  = (u16*)p;     p += (size_t)4 * 65536 * 2;      // 524,288
  int* flags = (int*)p;   p += 1024;
  size_t need = (size_t)(p - (char*)d_ws);
  if (need > ws_size) {                                    // sentinel: absmax ~1e6 => ws too small
    k_fill<<<256, 256, 0, stream>>>(out, out_size, 1.0e6f);
    return;
  }

  k_wi  <<<768,  256, 0, stream>>>(Wi, wth, wtl);
  k_zero<<<256,  256, 0, stream>>>((u32*)hb, (524288 + 1024) / 4);
  k_gemm<<<6144, 256, 0, stream>>>(x, wth, wtl, xi);
  k_rnn <<<G_,   256, 0, stream>>>(xi, Wh, bh, hb, flags, out);
}